// Round 3
// baseline (3804.214 us; speedup 1.0000x reference)
//
#include <hip/hip_runtime.h>

#define SLEN 2048
#define HDIM 4096
#define NHEADS 32
#define HEADD 128
#define FFDIM 13696
#define QKV3 12288
#define NGRP 107
#define ATT_SCALE 0.08838834764831845f

typedef __attribute__((ext_vector_type(4))) float f32x4;
typedef __attribute__((ext_vector_type(8))) _Float16 f16x8;
typedef __attribute__((ext_vector_type(4))) _Float16 f16x4;
typedef __attribute__((ext_vector_type(4))) int i32x4;

__device__ inline f32x4 zero4() { f32x4 v = {0.f, 0.f, 0.f, 0.f}; return v; }

__device__ inline f32x4 mfma16(f16x8 a, f16x8 b, f32x4 c) {
  return __builtin_amdgcn_mfma_f32_16x16x32_f16(a, b, c, 0, 0, 0);
}

// ---------------- RMSNorm: f32 in -> f16 out ----------------
__global__ __launch_bounds__(256)
void rmsnorm_k(const float* __restrict__ x, const float* __restrict__ w,
               _Float16* __restrict__ out)
{
  const int row = blockIdx.x;
  const int tid = threadIdx.x;
  const float* xr = x + (long)row * HDIM;
  f32x4 v[4];
  float ss = 0.f;
#pragma unroll
  for (int i = 0; i < 4; ++i) {
    v[i] = *(const f32x4*)(xr + (tid + 256 * i) * 4);
    ss += v[i][0]*v[i][0] + v[i][1]*v[i][1] + v[i][2]*v[i][2] + v[i][3]*v[i][3];
  }
#pragma unroll
  for (int m = 32; m > 0; m >>= 1) ss += __shfl_xor(ss, m, 64);
  __shared__ float red[4];
  if ((tid & 63) == 0) red[tid >> 6] = ss;
  __syncthreads();
  ss = red[0] + red[1] + red[2] + red[3];
  const float rstd = rsqrtf(ss * (1.f / HDIM) + 1e-6f);
  _Float16* op = out + (long)row * HDIM;
#pragma unroll
  for (int i = 0; i < 4; ++i) {
    const int c = (tid + 256 * i) * 4;
    const f32x4 wv = *(const f32x4*)(w + c);
    f16x4 o;
    o[0] = (_Float16)(v[i][0] * rstd * wv[0]);
    o[1] = (_Float16)(v[i][1] * rstd * wv[1]);
    o[2] = (_Float16)(v[i][2] * rstd * wv[2]);
    o[3] = (_Float16)(v[i][3] * rstd * wv[3]);
    *(f16x4*)(op + c) = o;
  }
}

// ---------------- NT GEMM: C[m,n] = sum_k A[m,k]*B[n,k] ----------------
// A: f16 [M][K]; B: f32 [N][K] (converted on stage). BM=BN=128, BK=64.
// EPI 0: store f16 to outh. EPI 1: outf = resid + acc (f32).
template<int EPI>
__global__ __launch_bounds__(256, 2)
void gemm_nt(const _Float16* __restrict__ A, const float* __restrict__ B,
             _Float16* __restrict__ outh, float* __restrict__ outf,
             const float* __restrict__ resid, int M, int N, int K)
{
  __shared__ alignas(16) char sA[128 * 128];  // [128 rows][64 f16], swizzled
  __shared__ alignas(16) char sB[128 * 128];
  const int tid = threadIdx.x;
  const int m0 = blockIdx.y * 128;
  const int n0 = blockIdx.x * 128;
  const int w = tid >> 6, lane = tid & 63, lr = lane & 15, lg = lane >> 4;
  const int wr = (w >> 1) * 64, wc = (w & 1) * 64;
  const int sr = tid >> 1, sh = tid & 1;
  const int swz = (sr & 7) << 4;

  f32x4 acc[4][4];
#pragma unroll
  for (int i = 0; i < 4; ++i)
#pragma unroll
    for (int j = 0; j < 4; ++j) acc[i][j] = zero4();

  const _Float16* arow = A + (long)(m0 + sr) * K;
  const float* brow = B + (long)(n0 + sr) * K;

  for (int k0 = 0; k0 < K; k0 += 64) {
    __syncthreads();
#pragma unroll
    for (int i = 0; i < 4; ++i) {
      const int kk = sh * 32 + i * 8;
      f16x8 va = *(const f16x8*)(arow + k0 + kk);
      *(f16x8*)(sA + sr * 128 + ((kk * 2) ^ swz)) = va;
      f32x4 v0 = *(const f32x4*)(brow + k0 + kk);
      f32x4 v1 = *(const f32x4*)(brow + k0 + kk + 4);
      f16x8 vb;
      vb[0] = (_Float16)v0[0]; vb[1] = (_Float16)v0[1];
      vb[2] = (_Float16)v0[2]; vb[3] = (_Float16)v0[3];
      vb[4] = (_Float16)v1[0]; vb[5] = (_Float16)v1[1];
      vb[6] = (_Float16)v1[2]; vb[7] = (_Float16)v1[3];
      *(f16x8*)(sB + sr * 128 + ((kk * 2) ^ swz)) = vb;
    }
    __syncthreads();
#pragma unroll
    for (int kc = 0; kc < 2; ++kc) {
      f16x8 af[4], bb[4];
#pragma unroll
      for (int i = 0; i < 4; ++i) {
        const int ra = wr + i * 16 + lr;
        af[i] = *(const f16x8*)(sA + ra * 128 + ((kc * 64 + lg * 16) ^ ((ra & 7) << 4)));
        const int rb = wc + i * 16 + lr;
        bb[i] = *(const f16x8*)(sB + rb * 128 + ((kc * 64 + lg * 16) ^ ((rb & 7) << 4)));
      }
#pragma unroll
      for (int i = 0; i < 4; ++i)
#pragma unroll
        for (int j = 0; j < 4; ++j)
          acc[i][j] = mfma16(af[i], bb[j], acc[i][j]);
    }
  }
#pragma unroll
  for (int i = 0; i < 4; ++i)
#pragma unroll
    for (int j = 0; j < 4; ++j)
#pragma unroll
      for (int r = 0; r < 4; ++r) {
        const int gr = m0 + wr + i * 16 + lg * 4 + r;  // C/D: row=(lg)*4+reg
        const int gc = n0 + wc + j * 16 + lr;          //      col=lane&15
        const long idx = (long)gr * N + gc;
        if (EPI == 0) outh[idx] = (_Float16)acc[i][j][r];
        else          outf[idx] = resid[idx] + acc[i][j][r];
      }
}

// ---------------- causal flash attention ----------------
// grid (head, qtile); 1 block = 64 q-rows of one head; 4 waves x 16 rows.
__global__ __launch_bounds__(256, 2)
void attn_fwd(const _Float16* __restrict__ qkv, _Float16* __restrict__ ctx)
{
  __shared__ alignas(16) char sK[64 * 256];   // [64 kv][128 d] f16, swizzled
  __shared__ alignas(16) char sV[128 * 128];  // [128 d][64 kv] f16 (transposed), swizzled
  __shared__ alignas(16) char sP[64 * 128];   // [64 q][64 kv] f16, swizzled

  const int head = blockIdx.x;
  const int qt = (int)gridDim.y - 1 - (int)blockIdx.y;  // heavy blocks first
  const int tid = threadIdx.x;
  const int w = tid >> 6, lane = tid & 63, lr = lane & 15, lg = lane >> 4;
  const int q0 = qt * 64;

  // Q fragments in registers (reused across all kv tiles)
  f16x8 qf[4];
  {
    const _Float16* qp = qkv + (long)(q0 + w * 16 + lr) * QKV3 + head * HEADD;
#pragma unroll
    for (int dc = 0; dc < 4; ++dc)
      qf[dc] = *(const f16x8*)(qp + dc * 32 + lg * 8);
  }

  f32x4 accO[8];
#pragma unroll
  for (int n = 0; n < 8; ++n) accO[n] = zero4();
  float mrow[4] = {-1e30f, -1e30f, -1e30f, -1e30f};
  float lrow[4] = {0.f, 0.f, 0.f, 0.f};

  for (int kt = 0; kt <= qt; ++kt) {
    const int kv0 = kt * 64;
    __syncthreads();
    {  // stage K [64][128]
      const int row = tid >> 2;
      const _Float16* src = qkv + (long)(kv0 + row) * QKV3 + HDIM + head * HEADD;
#pragma unroll
      for (int i = 0; i < 4; ++i) {
        const int ch = (tid & 3) + i * 4;
        f16x8 v = *(const f16x8*)(src + ch * 8);
        *(f16x8*)(sK + row * 256 + ((ch * 16) ^ ((row & 7) << 4))) = v;
      }
    }
    {  // stage V transposed -> sV[d][kv]
      const int kv = tid & 63;
      const int dblk = tid >> 6;
      const _Float16* src = qkv + (long)(kv0 + kv) * QKV3 + 2 * HDIM + head * HEADD;
#pragma unroll
      for (int i = 0; i < 4; ++i) {
        const int d0 = dblk * 32 + i * 8;
        f16x8 v = *(const f16x8*)(src + d0);
#pragma unroll
        for (int j = 0; j < 8; ++j) {
          const int d = d0 + j;
          *(_Float16*)(sV + d * 128 + ((kv * 2) ^ ((d & 7) << 4))) = v[j];
        }
      }
    }
    __syncthreads();

    // S = Q K^T  (wave's 16 q-rows x 64 kv)
    f32x4 s[4];
#pragma unroll
    for (int c = 0; c < 4; ++c) {
      s[c] = zero4();
#pragma unroll
      for (int dc = 0; dc < 4; ++dc) {
        const int rb = c * 16 + lr;
        f16x8 kf = *(const f16x8*)(sK + rb * 256 + ((dc * 64 + lg * 16) ^ ((rb & 7) << 4)));
        s[c] = mfma16(qf[dc], kf, s[c]);
      }
    }
    const bool diag = (kt == qt);
    float pm[4][4];
    float rmax[4] = {-1e30f, -1e30f, -1e30f, -1e30f};
#pragma unroll
    for (int c = 0; c < 4; ++c)
#pragma unroll
      for (int r = 0; r < 4; ++r) {
        float v = s[c][r] * ATT_SCALE;
        if (diag) {
          const int qg = w * 16 + lg * 4 + r;
          const int kg = c * 16 + lr;
          if (kg > qg) v = -1e30f;
        }
        pm[c][r] = v;
        rmax[r] = fmaxf(rmax[r], v);
      }
#pragma unroll
    for (int r = 0; r < 4; ++r) {
      float m = rmax[r];
      m = fmaxf(m, __shfl_xor(m, 1, 16));
      m = fmaxf(m, __shfl_xor(m, 2, 16));
      m = fmaxf(m, __shfl_xor(m, 4, 16));
      m = fmaxf(m, __shfl_xor(m, 8, 16));
      const float mn = fmaxf(mrow[r], m);
      const float sf = __expf(mrow[r] - mn);
      mrow[r] = mn;
      float rs = 0.f;
#pragma unroll
      for (int c = 0; c < 4; ++c) {
        const float p = __expf(pm[c][r] - mn);
        pm[c][r] = p;
        rs += p;
      }
      rs += __shfl_xor(rs, 1, 16);
      rs += __shfl_xor(rs, 2, 16);
      rs += __shfl_xor(rs, 4, 16);
      rs += __shfl_xor(rs, 8, 16);
      lrow[r] = lrow[r] * sf + rs;
#pragma unroll
      for (int n = 0; n < 8; ++n) accO[n][r] *= sf;
    }
    // P -> LDS (own wave stripe only; no barrier needed)
#pragma unroll
    for (int c = 0; c < 4; ++c)
#pragma unroll
      for (int r = 0; r < 4; ++r) {
        const int prow = w * 16 + lg * 4 + r;
        const int pcol = c * 16 + lr;
        *(_Float16*)(sP + prow * 128 + ((pcol * 2) ^ ((prow & 7) << 4))) = (_Float16)pm[c][r];
      }
    // O += P V
#pragma unroll
    for (int kc = 0; kc < 2; ++kc) {
      const int pr = w * 16 + lr;
      f16x8 pf = *(const f16x8*)(sP + pr * 128 + ((kc * 64 + lg * 16) ^ ((pr & 7) << 4)));
#pragma unroll
      for (int n = 0; n < 8; ++n) {
        const int vr = n * 16 + lr;
        f16x8 vf = *(const f16x8*)(sV + vr * 128 + ((kc * 64 + lg * 16) ^ ((vr & 7) << 4)));
        accO[n] = mfma16(pf, vf, accO[n]);
      }
    }
  }
  _Float16* cp = ctx;
#pragma unroll
  for (int n = 0; n < 8; ++n)
#pragma unroll
    for (int r = 0; r < 4; ++r) {
      const int gr = q0 + w * 16 + lg * 4 + r;
      const int gc = head * HEADD + n * 16 + lr;
      cp[(long)gr * HDIM + gc] = (_Float16)(accO[n][r] / lrow[r]);
    }
}

// ---------------- h4h GEMM with fused SwiGLU ----------------
// block: 128 rows x 64 act-cols; gate rows n0+r, up rows FF+n0+r of w_h4h.
__global__ __launch_bounds__(256, 2)
void gemm_h4h(const _Float16* __restrict__ A, const float* __restrict__ B,
              _Float16* __restrict__ act, int M, int K)
{
  __shared__ alignas(16) char sA[128 * 128];
  __shared__ alignas(16) char sB[128 * 128];  // rows 0-63 gate, 64-127 up
  const int tid = threadIdx.x;
  const int m0 = blockIdx.y * 128;
  const int n0 = blockIdx.x * 64;
  const int w = tid >> 6, lane = tid & 63, lr = lane & 15, lg = lane >> 4;
  const int wr = (w >> 1) * 64, wc = (w & 1) * 32;
  const int sr = tid >> 1, sh = tid & 1;
  const int swz = (sr & 7) << 4;

  f32x4 ag[4][2], au[4][2];
#pragma unroll
  for (int i = 0; i < 4; ++i)
#pragma unroll
    for (int j = 0; j < 2; ++j) { ag[i][j] = zero4(); au[i][j] = zero4(); }

  const _Float16* arow = A + (long)(m0 + sr) * K;
  const float* brow = B + (long)(sr < 64 ? (n0 + sr) : (FFDIM + n0 + sr - 64)) * K;

  for (int k0 = 0; k0 < K; k0 += 64) {
    __syncthreads();
#pragma unroll
    for (int i = 0; i < 4; ++i) {
      const int kk = sh * 32 + i * 8;
      f16x8 va = *(const f16x8*)(arow + k0 + kk);
      *(f16x8*)(sA + sr * 128 + ((kk * 2) ^ swz)) = va;
      f32x4 v0 = *(const f32x4*)(brow + k0 + kk);
      f32x4 v1 = *(const f32x4*)(brow + k0 + kk + 4);
      f16x8 vb;
      vb[0] = (_Float16)v0[0]; vb[1] = (_Float16)v0[1];
      vb[2] = (_Float16)v0[2]; vb[3] = (_Float16)v0[3];
      vb[4] = (_Float16)v1[0]; vb[5] = (_Float16)v1[1];
      vb[6] = (_Float16)v1[2]; vb[7] = (_Float16)v1[3];
      *(f16x8*)(sB + sr * 128 + ((kk * 2) ^ swz)) = vb;
    }
    __syncthreads();
#pragma unroll
    for (int kc = 0; kc < 2; ++kc) {
      f16x8 af[4], bg[2], bu[2];
#pragma unroll
      for (int i = 0; i < 4; ++i) {
        const int ra = wr + i * 16 + lr;
        af[i] = *(const f16x8*)(sA + ra * 128 + ((kc * 64 + lg * 16) ^ ((ra & 7) << 4)));
      }
#pragma unroll
      for (int j = 0; j < 2; ++j) {
        const int rg = wc + j * 16 + lr;
        bg[j] = *(const f16x8*)(sB + rg * 128 + ((kc * 64 + lg * 16) ^ ((rg & 7) << 4)));
        const int ru = 64 + wc + j * 16 + lr;
        bu[j] = *(const f16x8*)(sB + ru * 128 + ((kc * 64 + lg * 16) ^ ((ru & 7) << 4)));
      }
#pragma unroll
      for (int i = 0; i < 4; ++i)
#pragma unroll
        for (int j = 0; j < 2; ++j) {
          ag[i][j] = mfma16(af[i], bg[j], ag[i][j]);
          au[i][j] = mfma16(af[i], bu[j], au[i][j]);
        }
    }
  }
#pragma unroll
  for (int i = 0; i < 4; ++i)
#pragma unroll
    for (int j = 0; j < 2; ++j)
#pragma unroll
      for (int r = 0; r < 4; ++r) {
        const float g = ag[i][j][r];
        const float u = au[i][j][r];
        const float sv = g / (1.f + __expf(-g)) * u;
        const int gr = m0 + wr + i * 16 + lg * 4 + r;
        const int gc = n0 + wc + j * 16 + lr;
        act[(long)gr * FFDIM + gc] = (_Float16)sv;
      }
}

// ---------------- down GEMM with on-the-fly int4 dequant ----------------
__global__ __launch_bounds__(256, 2)
void gemm_down(const _Float16* __restrict__ A, const int* __restrict__ qw,
               const int* __restrict__ qz, const float* __restrict__ sc,
               const float* __restrict__ x1, const float* __restrict__ bias,
               float* __restrict__ out, int M, int N, int K)
{
  __shared__ alignas(16) char sA[128 * 128];
  __shared__ alignas(16) char sB[128 * 128];
  const int tid = threadIdx.x;
  const int m0 = blockIdx.y * 128;
  const int n0 = blockIdx.x * 128;
  const int w = tid >> 6, lane = tid & 63, lr = lane & 15, lg = lane >> 4;
  const int wr = (w >> 1) * 64, wc = (w & 1) * 64;
  const int sr = tid >> 1, sh = tid & 1;
  const int swz = (sr & 7) << 4;

  f32x4 acc[4][4];
#pragma unroll
  for (int i = 0; i < 4; ++i)
#pragma unroll
    for (int j = 0; j < 4; ++j) acc[i][j] = zero4();

  const _Float16* arow = A + (long)(m0 + sr) * K;
  const int nrow = n0 + sr;
  const int* qrowp = qw + (long)nrow * (K >> 1);

  for (int k0 = 0; k0 < K; k0 += 64) {
    const int g0 = k0 >> 7;                 // 64 | GS=128 -> one group per tile
    const float s = sc[nrow * NGRP + g0];
    const float z = (float)qz[nrow * NGRP + g0];
    __syncthreads();
#pragma unroll
    for (int i = 0; i < 4; ++i) {
      const int kk = sh * 32 + i * 8;
      f16x8 va = *(const f16x8*)(arow + k0 + kk);
      *(f16x8*)(sA + sr * 128 + ((kk * 2) ^ swz)) = va;
    }
#pragma unroll
    for (int u4 = 0; u4 < 4; ++u4) {
      const i32x4 q = *(const i32x4*)(qrowp + ((k0 + sh * 32) >> 1) + u4 * 4);
      f16x8 t;
#pragma unroll
      for (int e = 0; e < 4; ++e) {
        const int v = q[e];
        t[e * 2]     = (_Float16)(((float)((v >> 4) & 15) - z) * s);  // hi nibble first
        t[e * 2 + 1] = (_Float16)(((float)(v & 15) - z) * s);
      }
      const int kk = sh * 32 + u4 * 8;
      *(f16x8*)(sB + sr * 128 + ((kk * 2) ^ swz)) = t;
    }
    __syncthreads();
#pragma unroll
    for (int kc = 0; kc < 2; ++kc) {
      f16x8 af[4], bb[4];
#pragma unroll
      for (int i = 0; i < 4; ++i) {
        const int ra = wr + i * 16 + lr;
        af[i] = *(const f16x8*)(sA + ra * 128 + ((kc * 64 + lg * 16) ^ ((ra & 7) << 4)));
        const int rb = wc + i * 16 + lr;
        bb[i] = *(const f16x8*)(sB + rb * 128 + ((kc * 64 + lg * 16) ^ ((rb & 7) << 4)));
      }
#pragma unroll
      for (int i = 0; i < 4; ++i)
#pragma unroll
        for (int j = 0; j < 4; ++j)
          acc[i][j] = mfma16(af[i], bb[j], acc[i][j]);
    }
  }
#pragma unroll
  for (int i = 0; i < 4; ++i)
#pragma unroll
    for (int j = 0; j < 4; ++j)
#pragma unroll
      for (int r = 0; r < 4; ++r) {
        const int gr = m0 + wr + i * 16 + lg * 4 + r;
        const int gc = n0 + wc + j * 16 + lr;
        const long idx = (long)gr * N + gc;
        out[idx] = x1[idx] + bias[gc] + acc[i][j][r];
      }
}

extern "C" void kernel_launch(void* const* d_in, const int* in_sizes, int n_in,
                              void* d_out, int out_size, void* d_ws, size_t ws_size,
                              hipStream_t stream) {
  const float* hidden   = (const float*)d_in[0];
  const float* w_norm1  = (const float*)d_in[1];
  const float* w_norm2  = (const float*)d_in[2];
  const float* w_qkv    = (const float*)d_in[3];
  const float* w_attn   = (const float*)d_in[4];
  const float* w_h4h    = (const float*)d_in[5];
  const float* scales   = (const float*)d_in[6];
  const float* bias4h   = (const float*)d_in[7];
  const int*   qweight  = (const int*)d_in[8];
  const int*   qzeros   = (const int*)d_in[9];
  float* out = (float*)d_out;

  char* ws = (char*)d_ws;
  float*     x1   = (float*)ws;                          // 33,554,432 B
  _Float16*  ln   = (_Float16*)(ws + 33554432);          // 16,777,216 B
  _Float16*  qkvb = (_Float16*)(ws + 50331648);          // 50,331,648 B
  _Float16*  ctx  = (_Float16*)(ws + 100663296);         // 16,777,216 B
  _Float16*  act  = (_Float16*)(ws + 50331648);          // 56,098,816 B (aliases dead qkv+ctx)

  rmsnorm_k<<<SLEN, 256, 0, stream>>>(hidden, w_norm1, ln);
  gemm_nt<0><<<dim3(QKV3 / 128, SLEN / 128), 256, 0, stream>>>(
      ln, w_qkv, qkvb, nullptr, nullptr, SLEN, QKV3, HDIM);
  attn_fwd<<<dim3(NHEADS, SLEN / 64), 256, 0, stream>>>(qkvb, ctx);
  gemm_nt<1><<<dim3(HDIM / 128, SLEN / 128), 256, 0, stream>>>(
      ctx, w_attn, nullptr, x1, hidden, SLEN, HDIM, HDIM);
  rmsnorm_k<<<SLEN, 256, 0, stream>>>(x1, w_norm2, ln);
  gemm_h4h<<<dim3(FFDIM / 64, SLEN / 128), 256, 0, stream>>>(ln, w_h4h, act, SLEN, HDIM);
  gemm_down<<<dim3(HDIM / 128, SLEN / 128), 256, 0, stream>>>(
      act, qweight, qzeros, scales, x1, bias4h, out, SLEN, HDIM, FFDIM);
}

// Round 6
// 2322.685 us; speedup vs baseline: 1.6379x; 1.6379x over previous
//
#include <hip/hip_runtime.h>

#define SLEN 2048
#define HDIM 4096
#define NHEADS 32
#define HEADD 128
#define FFDIM 13696
#define QKV3 12288
#define NGRP 107
#define ATT_SCALE 0.08838834764831845f

typedef __attribute__((ext_vector_type(4))) float f32x4;
typedef __attribute__((ext_vector_type(8))) _Float16 f16x8;
typedef __attribute__((ext_vector_type(4))) _Float16 f16x4;
typedef __attribute__((ext_vector_type(4))) int i32x4;

__device__ inline f32x4 zero4() { f32x4 v = {0.f, 0.f, 0.f, 0.f}; return v; }

__device__ inline f32x4 mfma16(f16x8 a, f16x8 b, f32x4 c) {
  return __builtin_amdgcn_mfma_f32_16x16x32_f16(a, b, c, 0, 0, 0);
}

// ---------------- f32 -> f16 bulk convert (weights) ----------------
__global__ __launch_bounds__(256)
void cvt_f32_f16(const float* __restrict__ in, _Float16* __restrict__ out, long n)
{
  long i = ((long)blockIdx.x * 256 + threadIdx.x) * 8;
  const long stride = (long)gridDim.x * 256 * 8;
  for (; i < n; i += stride) {
    f32x4 a = *(const f32x4*)(in + i);
    f32x4 b = *(const f32x4*)(in + i + 4);
    f16x8 o;
    o[0] = (_Float16)a[0]; o[1] = (_Float16)a[1];
    o[2] = (_Float16)a[2]; o[3] = (_Float16)a[3];
    o[4] = (_Float16)b[0]; o[5] = (_Float16)b[1];
    o[6] = (_Float16)b[2]; o[7] = (_Float16)b[3];
    *(f16x8*)(out + i) = o;
  }
}

// ---------------- RMSNorm: f32 in -> f16 out ----------------
__global__ __launch_bounds__(256)
void rmsnorm_k(const float* __restrict__ x, const float* __restrict__ w,
               _Float16* __restrict__ out)
{
  const int row = blockIdx.x;
  const int tid = threadIdx.x;
  const float* xr = x + (long)row * HDIM;
  f32x4 v[4];
  float ss = 0.f;
#pragma unroll
  for (int i = 0; i < 4; ++i) {
    v[i] = *(const f32x4*)(xr + (tid + 256 * i) * 4);
    ss += v[i][0]*v[i][0] + v[i][1]*v[i][1] + v[i][2]*v[i][2] + v[i][3]*v[i][3];
  }
#pragma unroll
  for (int m = 32; m > 0; m >>= 1) ss += __shfl_xor(ss, m, 64);
  __shared__ float red[4];
  if ((tid & 63) == 0) red[tid >> 6] = ss;
  __syncthreads();
  ss = red[0] + red[1] + red[2] + red[3];
  const float rstd = rsqrtf(ss * (1.f / HDIM) + 1e-6f);
  _Float16* op = out + (long)row * HDIM;
#pragma unroll
  for (int i = 0; i < 4; ++i) {
    const int c = (tid + 256 * i) * 4;
    const f32x4 wv = *(const f32x4*)(w + c);
    f16x4 o;
    o[0] = (_Float16)(v[i][0] * rstd * wv[0]);
    o[1] = (_Float16)(v[i][1] * rstd * wv[1]);
    o[2] = (_Float16)(v[i][2] * rstd * wv[2]);
    o[3] = (_Float16)(v[i][3] * rstd * wv[3]);
    *(f16x4*)(op + c) = o;
  }
}

// ---------------- NT GEMM: C[m,n] = sum_k A[m,k]*B[n,k] ----------------
// A: f16 [M][K]; B: f32 or f16 [N][K]. BM=BN=128, BK=64.
// Grid: x = m-tile (fast -> weight-panel reuse in L3), y = n-tile.
// EPI 0: store f16 to outh. EPI 1: outf = resid + acc (f32).
template<int EPI, bool F16B>
__global__ __launch_bounds__(256, 2)
void gemm_nt(const _Float16* __restrict__ A, const void* __restrict__ B,
             _Float16* __restrict__ outh, float* __restrict__ outf,
             const float* __restrict__ resid, int M, int N, int K)
{
  __shared__ alignas(16) char sA[128 * 128];  // [128 rows][64 f16], swizzled
  __shared__ alignas(16) char sB[128 * 128];
  const int tid = threadIdx.x;
  const int m0 = blockIdx.x * 128;
  const int n0 = blockIdx.y * 128;
  const int w = tid >> 6, lane = tid & 63, lr = lane & 15, lg = lane >> 4;
  const int wr = (w >> 1) * 64, wc = (w & 1) * 64;
  const int sr = tid >> 1, sh = tid & 1;
  const int swz = (sr & 7) << 4;

  f32x4 acc[4][4];
#pragma unroll
  for (int i = 0; i < 4; ++i)
#pragma unroll
    for (int j = 0; j < 4; ++j) acc[i][j] = zero4();

  const _Float16* arow = A + (long)(m0 + sr) * K;
  const float* brow32 = F16B ? nullptr : ((const float*)B + (long)(n0 + sr) * K);
  const _Float16* brow16 = F16B ? ((const _Float16*)B + (long)(n0 + sr) * K) : nullptr;

  for (int k0 = 0; k0 < K; k0 += 64) {
    __syncthreads();
#pragma unroll
    for (int i = 0; i < 4; ++i) {
      const int kk = sh * 32 + i * 8;
      f16x8 va = *(const f16x8*)(arow + k0 + kk);
      *(f16x8*)(sA + sr * 128 + ((kk * 2) ^ swz)) = va;
      f16x8 vb;
      if constexpr (F16B) {
        vb = *(const f16x8*)(brow16 + k0 + kk);
      } else {
        f32x4 v0 = *(const f32x4*)(brow32 + k0 + kk);
        f32x4 v1 = *(const f32x4*)(brow32 + k0 + kk + 4);
        vb[0] = (_Float16)v0[0]; vb[1] = (_Float16)v0[1];
        vb[2] = (_Float16)v0[2]; vb[3] = (_Float16)v0[3];
        vb[4] = (_Float16)v1[0]; vb[5] = (_Float16)v1[1];
        vb[6] = (_Float16)v1[2]; vb[7] = (_Float16)v1[3];
      }
      *(f16x8*)(sB + sr * 128 + ((kk * 2) ^ swz)) = vb;
    }
    __syncthreads();
#pragma unroll
    for (int kc = 0; kc < 2; ++kc) {
      f16x8 af[4], bb[4];
#pragma unroll
      for (int i = 0; i < 4; ++i) {
        const int ra = wr + i * 16 + lr;
        af[i] = *(const f16x8*)(sA + ra * 128 + ((kc * 64 + lg * 16) ^ ((ra & 7) << 4)));
        const int rb = wc + i * 16 + lr;
        bb[i] = *(const f16x8*)(sB + rb * 128 + ((kc * 64 + lg * 16) ^ ((rb & 7) << 4)));
      }
#pragma unroll
      for (int i = 0; i < 4; ++i)
#pragma unroll
        for (int j = 0; j < 4; ++j)
          acc[i][j] = mfma16(af[i], bb[j], acc[i][j]);
    }
  }
#pragma unroll
  for (int i = 0; i < 4; ++i)
#pragma unroll
    for (int j = 0; j < 4; ++j)
#pragma unroll
      for (int r = 0; r < 4; ++r) {
        const int gr = m0 + wr + i * 16 + lg * 4 + r;  // C/D: row=(lg)*4+reg
        const int gc = n0 + wc + j * 16 + lr;          //      col=lane&15
        const long idx = (long)gr * N + gc;
        if (EPI == 0) outh[idx] = (_Float16)acc[i][j][r];
        else          outf[idx] = resid[idx] + acc[i][j][r];
      }
}

// ---------------- causal flash attention ----------------
// grid (head, qtile); 1 block = 64 q-rows of one head; 4 waves x 16 rows.
__global__ __launch_bounds__(256, 2)
void attn_fwd(const _Float16* __restrict__ qkv, _Float16* __restrict__ ctx)
{
  __shared__ alignas(16) char sK[64 * 256];   // [64 kv][128 d] f16, swizzled
  __shared__ alignas(16) char sV[128 * 128];  // [128 d][64 kv] f16 (transposed), swizzled
  __shared__ alignas(16) char sP[64 * 128];   // [64 q][64 kv] f16, swizzled

  const int head = blockIdx.x;
  const int qt = (int)gridDim.y - 1 - (int)blockIdx.y;  // heavy blocks first
  const int tid = threadIdx.x;
  const int w = tid >> 6, lane = tid & 63, lr = lane & 15, lg = lane >> 4;
  const int q0 = qt * 64;

  // Q fragments in registers (reused across all kv tiles)
  f16x8 qf[4];
  {
    const _Float16* qp = qkv + (long)(q0 + w * 16 + lr) * QKV3 + head * HEADD;
#pragma unroll
    for (int dc = 0; dc < 4; ++dc)
      qf[dc] = *(const f16x8*)(qp + dc * 32 + lg * 8);
  }

  f32x4 accO[8];
#pragma unroll
  for (int n = 0; n < 8; ++n) accO[n] = zero4();
  float mrow[4] = {-1e30f, -1e30f, -1e30f, -1e30f};
  float lrow[4] = {0.f, 0.f, 0.f, 0.f};

  for (int kt = 0; kt <= qt; ++kt) {
    const int kv0 = kt * 64;
    __syncthreads();
    {  // stage K [64][128]
      const int row = tid >> 2;
      const _Float16* src = qkv + (long)(kv0 + row) * QKV3 + HDIM + head * HEADD;
#pragma unroll
      for (int i = 0; i < 4; ++i) {
        const int ch = (tid & 3) + i * 4;
        f16x8 v = *(const f16x8*)(src + ch * 8);
        *(f16x8*)(sK + row * 256 + ((ch * 16) ^ ((row & 7) << 4))) = v;
      }
    }
    {  // stage V transposed -> sV[d][kv]
      const int kv = tid & 63;
      const int dblk = tid >> 6;
      const _Float16* src = qkv + (long)(kv0 + kv) * QKV3 + 2 * HDIM + head * HEADD;
#pragma unroll
      for (int i = 0; i < 4; ++i) {
        const int d0 = dblk * 32 + i * 8;
        f16x8 v = *(const f16x8*)(src + d0);
#pragma unroll
        for (int j = 0; j < 8; ++j) {
          const int d = d0 + j;
          *(_Float16*)(sV + d * 128 + ((kv * 2) ^ ((d & 7) << 4))) = v[j];
        }
      }
    }
    __syncthreads();

    // S = Q K^T  (wave's 16 q-rows x 64 kv)
    f32x4 s[4];
#pragma unroll
    for (int c = 0; c < 4; ++c) {
      s[c] = zero4();
#pragma unroll
      for (int dc = 0; dc < 4; ++dc) {
        const int rb = c * 16 + lr;
        f16x8 kf = *(const f16x8*)(sK + rb * 256 + ((dc * 64 + lg * 16) ^ ((rb & 7) << 4)));
        s[c] = mfma16(qf[dc], kf, s[c]);
      }
    }
    const bool diag = (kt == qt);
    float pm[4][4];
    float rmax[4] = {-1e30f, -1e30f, -1e30f, -1e30f};
#pragma unroll
    for (int c = 0; c < 4; ++c)
#pragma unroll
      for (int r = 0; r < 4; ++r) {
        float v = s[c][r] * ATT_SCALE;
        if (diag) {
          const int qg = w * 16 + lg * 4 + r;
          const int kg = c * 16 + lr;
          if (kg > qg) v = -1e30f;
        }
        pm[c][r] = v;
        rmax[r] = fmaxf(rmax[r], v);
      }
#pragma unroll
    for (int r = 0; r < 4; ++r) {
      float m = rmax[r];
      m = fmaxf(m, __shfl_xor(m, 1, 16));
      m = fmaxf(m, __shfl_xor(m, 2, 16));
      m = fmaxf(m, __shfl_xor(m, 4, 16));
      m = fmaxf(m, __shfl_xor(m, 8, 16));
      const float mn = fmaxf(mrow[r], m);
      const float sf = __expf(mrow[r] - mn);
      mrow[r] = mn;
      float rs = 0.f;
#pragma unroll
      for (int c = 0; c < 4; ++c) {
        const float p = __expf(pm[c][r] - mn);
        pm[c][r] = p;
        rs += p;
      }
      rs += __shfl_xor(rs, 1, 16);
      rs += __shfl_xor(rs, 2, 16);
      rs += __shfl_xor(rs, 4, 16);
      rs += __shfl_xor(rs, 8, 16);
      lrow[r] = lrow[r] * sf + rs;
#pragma unroll
      for (int n = 0; n < 8; ++n) accO[n][r] *= sf;
    }
    // P -> LDS (own wave stripe only; no barrier needed)
#pragma unroll
    for (int c = 0; c < 4; ++c)
#pragma unroll
      for (int r = 0; r < 4; ++r) {
        const int prow = w * 16 + lg * 4 + r;
        const int pcol = c * 16 + lr;
        *(_Float16*)(sP + prow * 128 + ((pcol * 2) ^ ((prow & 7) << 4))) = (_Float16)pm[c][r];
      }
    // O += P V
#pragma unroll
    for (int kc = 0; kc < 2; ++kc) {
      const int pr = w * 16 + lr;
      f16x8 pf = *(const f16x8*)(sP + pr * 128 + ((kc * 64 + lg * 16) ^ ((pr & 7) << 4)));
#pragma unroll
      for (int n = 0; n < 8; ++n) {
        const int vr = n * 16 + lr;
        f16x8 vf = *(const f16x8*)(sV + vr * 128 + ((kc * 64 + lg * 16) ^ ((vr & 7) << 4)));
        accO[n] = mfma16(pf, vf, accO[n]);
      }
    }
  }
  _Float16* cp = ctx;
#pragma unroll
  for (int n = 0; n < 8; ++n)
#pragma unroll
    for (int r = 0; r < 4; ++r) {
      const int gr = q0 + w * 16 + lg * 4 + r;
      const int gc = head * HEADD + n * 16 + lr;
      cp[(long)gr * HDIM + gc] = (_Float16)(accO[n][r] / lrow[r]);
    }
}

// ---------------- h4h GEMM with fused SwiGLU ----------------
// block: 128 rows x 64 act-cols; gate rows n0+r, up rows FF+n0+r of w_h4h.
// Grid: x = m-tile (fast), y = ff-panel.
template<bool F16B>
__global__ __launch_bounds__(256, 2)
void gemm_h4h(const _Float16* __restrict__ A, const void* __restrict__ B,
              _Float16* __restrict__ act, int M, int K)
{
  __shared__ alignas(16) char sA[128 * 128];
  __shared__ alignas(16) char sB[128 * 128];  // rows 0-63 gate, 64-127 up
  const int tid = threadIdx.x;
  const int m0 = blockIdx.x * 128;
  const int n0 = blockIdx.y * 64;
  const int w = tid >> 6, lane = tid & 63, lr = lane & 15, lg = lane >> 4;
  const int wr = (w >> 1) * 64, wc = (w & 1) * 32;
  const int sr = tid >> 1, sh = tid & 1;
  const int swz = (sr & 7) << 4;

  f32x4 ag[4][2], au[4][2];
#pragma unroll
  for (int i = 0; i < 4; ++i)
#pragma unroll
    for (int j = 0; j < 2; ++j) { ag[i][j] = zero4(); au[i][j] = zero4(); }

  const _Float16* arow = A + (long)(m0 + sr) * K;
  const long brbase = (long)(sr < 64 ? (n0 + sr) : (FFDIM + n0 + sr - 64)) * K;
  const float* brow32 = F16B ? nullptr : ((const float*)B + brbase);
  const _Float16* brow16 = F16B ? ((const _Float16*)B + brbase) : nullptr;

  for (int k0 = 0; k0 < K; k0 += 64) {
    __syncthreads();
#pragma unroll
    for (int i = 0; i < 4; ++i) {
      const int kk = sh * 32 + i * 8;
      f16x8 va = *(const f16x8*)(arow + k0 + kk);
      *(f16x8*)(sA + sr * 128 + ((kk * 2) ^ swz)) = va;
      f16x8 vb;
      if constexpr (F16B) {
        vb = *(const f16x8*)(brow16 + k0 + kk);
      } else {
        f32x4 v0 = *(const f32x4*)(brow32 + k0 + kk);
        f32x4 v1 = *(const f32x4*)(brow32 + k0 + kk + 4);
        vb[0] = (_Float16)v0[0]; vb[1] = (_Float16)v0[1];
        vb[2] = (_Float16)v0[2]; vb[3] = (_Float16)v0[3];
        vb[4] = (_Float16)v1[0]; vb[5] = (_Float16)v1[1];
        vb[6] = (_Float16)v1[2]; vb[7] = (_Float16)v1[3];
      }
      *(f16x8*)(sB + sr * 128 + ((kk * 2) ^ swz)) = vb;
    }
    __syncthreads();
#pragma unroll
    for (int kc = 0; kc < 2; ++kc) {
      f16x8 af[4], bg[2], bu[2];
#pragma unroll
      for (int i = 0; i < 4; ++i) {
        const int ra = wr + i * 16 + lr;
        af[i] = *(const f16x8*)(sA + ra * 128 + ((kc * 64 + lg * 16) ^ ((ra & 7) << 4)));
      }
#pragma unroll
      for (int j = 0; j < 2; ++j) {
        const int rg = wc + j * 16 + lr;
        bg[j] = *(const f16x8*)(sB + rg * 128 + ((kc * 64 + lg * 16) ^ ((rg & 7) << 4)));
        const int ru = 64 + wc + j * 16 + lr;
        bu[j] = *(const f16x8*)(sB + ru * 128 + ((kc * 64 + lg * 16) ^ ((ru & 7) << 4)));
      }
#pragma unroll
      for (int i = 0; i < 4; ++i)
#pragma unroll
        for (int j = 0; j < 2; ++j) {
          ag[i][j] = mfma16(af[i], bg[j], ag[i][j]);
          au[i][j] = mfma16(af[i], bu[j], au[i][j]);
        }
    }
  }
#pragma unroll
  for (int i = 0; i < 4; ++i)
#pragma unroll
    for (int j = 0; j < 2; ++j)
#pragma unroll
      for (int r = 0; r < 4; ++r) {
        const float g = ag[i][j][r];
        const float u = au[i][j][r];
        const float sv = g / (1.f + __expf(-g)) * u;
        const int gr = m0 + wr + i * 16 + lg * 4 + r;
        const int gc = n0 + wc + j * 16 + lr;
        act[(long)gr * FFDIM + gc] = (_Float16)sv;
      }
}

// ---------------- down GEMM with on-the-fly int4 dequant ----------------
// Grid: x = m-tile (fast), y = h-panel.
__global__ __launch_bounds__(256, 2)
void gemm_down(const _Float16* __restrict__ A, const int* __restrict__ qw,
               const int* __restrict__ qz, const float* __restrict__ sc,
               const float* __restrict__ x1, const float* __restrict__ bias,
               float* __restrict__ out, int M, int N, int K)
{
  __shared__ alignas(16) char sA[128 * 128];
  __shared__ alignas(16) char sB[128 * 128];
  const int tid = threadIdx.x;
  const int m0 = blockIdx.x * 128;
  const int n0 = blockIdx.y * 128;
  const int w = tid >> 6, lane = tid & 63, lr = lane & 15, lg = lane >> 4;
  const int wr = (w >> 1) * 64, wc = (w & 1) * 64;
  const int sr = tid >> 1, sh = tid & 1;
  const int swz = (sr & 7) << 4;

  f32x4 acc[4][4];
#pragma unroll
  for (int i = 0; i < 4; ++i)
#pragma unroll
    for (int j = 0; j < 4; ++j) acc[i][j] = zero4();

  const _Float16* arow = A + (long)(m0 + sr) * K;
  const int nrow = n0 + sr;
  const int* qrowp = qw + (long)nrow * (K >> 1);

  for (int k0 = 0; k0 < K; k0 += 64) {
    const int g0 = k0 >> 7;                 // 64 | GS=128 -> one group per tile
    const float s = sc[nrow * NGRP + g0];
    const float z = (float)qz[nrow * NGRP + g0];
    __syncthreads();
#pragma unroll
    for (int i = 0; i < 4; ++i) {
      const int kk = sh * 32 + i * 8;
      f16x8 va = *(const f16x8*)(arow + k0 + kk);
      *(f16x8*)(sA + sr * 128 + ((kk * 2) ^ swz)) = va;
    }
#pragma unroll
    for (int u4 = 0; u4 < 4; ++u4) {
      const i32x4 q = *(const i32x4*)(qrowp + ((k0 + sh * 32) >> 1) + u4 * 4);
      f16x8 t;
#pragma unroll
      for (int e = 0; e < 4; ++e) {
        const int v = q[e];
        t[e * 2]     = (_Float16)(((float)((v >> 4) & 15) - z) * s);  // hi nibble first
        t[e * 2 + 1] = (_Float16)(((float)(v & 15) - z) * s);
      }
      const int kk = sh * 32 + u4 * 8;
      *(f16x8*)(sB + sr * 128 + ((kk * 2) ^ swz)) = t;
    }
    __syncthreads();
#pragma unroll
    for (int kc = 0; kc < 2; ++kc) {
      f16x8 af[4], bb[4];
#pragma unroll
      for (int i = 0; i < 4; ++i) {
        const int ra = wr + i * 16 + lr;
        af[i] = *(const f16x8*)(sA + ra * 128 + ((kc * 64 + lg * 16) ^ ((ra & 7) << 4)));
        const int rb = wc + i * 16 + lr;
        bb[i] = *(const f16x8*)(sB + rb * 128 + ((kc * 64 + lg * 16) ^ ((rb & 7) << 4)));
      }
#pragma unroll
      for (int i = 0; i < 4; ++i)
#pragma unroll
        for (int j = 0; j < 4; ++j)
          acc[i][j] = mfma16(af[i], bb[j], acc[i][j]);
    }
  }
#pragma unroll
  for (int i = 0; i < 4; ++i)
#pragma unroll
    for (int j = 0; j < 4; ++j)
#pragma unroll
      for (int r = 0; r < 4; ++r) {
        const int gr = m0 + wr + i * 16 + lg * 4 + r;
        const int gc = n0 + wc + j * 16 + lr;
        const long idx = (long)gr * N + gc;
        out[idx] = x1[idx] + bias[gc] + acc[i][j][r];
      }
}

extern "C" void kernel_launch(void* const* d_in, const int* in_sizes, int n_in,
                              void* d_out, int out_size, void* d_ws, size_t ws_size,
                              hipStream_t stream) {
  const float* hidden   = (const float*)d_in[0];
  const float* w_norm1  = (const float*)d_in[1];
  const float* w_norm2  = (const float*)d_in[2];
  const float* w_qkv    = (const float*)d_in[3];
  const float* w_attn   = (const float*)d_in[4];
  const float* w_h4h    = (const float*)d_in[5];
  const float* scales   = (const float*)d_in[6];
  const float* bias4h   = (const float*)d_in[7];
  const int*   qweight  = (const int*)d_in[8];
  const int*   qzeros   = (const int*)d_in[9];
  float* out = (float*)d_out;

  char* ws = (char*)d_ws;
  float*     x1   = (float*)ws;                          // [0, 32M)
  _Float16*  ln   = (_Float16*)(ws + 33554432);          // [32M, 48M)
  _Float16*  qkvb = (_Float16*)(ws + 50331648);          // [48M, 96M)
  _Float16*  ctx  = (_Float16*)(ws + 100663296);         // [96M, 112M)
  _Float16*  act  = (_Float16*)(ws + 50331648);          // aliases dead qkv+ctx

  // Optional f16 weight cache (only if workspace is large enough).
  const bool cvt = ws_size >= 476053504ULL;
  _Float16* wqkv16 = (_Float16*)(ws + 117440512);        // 100,663,296 B
  _Float16* watt16 = (_Float16*)(ws + 218103808);        //  33,554,432 B
  _Float16* wh4h16 = (_Float16*)(ws + 251658240);        // 224,395,264 B

  if (cvt) {
    cvt_f32_f16<<<2048, 256, 0, stream>>>(w_qkv, wqkv16, (long)QKV3 * HDIM);
    cvt_f32_f16<<<2048, 256, 0, stream>>>(w_attn, watt16, (long)HDIM * HDIM);
    cvt_f32_f16<<<2048, 256, 0, stream>>>(w_h4h, wh4h16, (long)2 * FFDIM * HDIM);
  }

  rmsnorm_k<<<SLEN, 256, 0, stream>>>(hidden, w_norm1, ln);
  if (cvt)
    gemm_nt<0, true><<<dim3(SLEN / 128, QKV3 / 128), 256, 0, stream>>>(
        ln, wqkv16, qkvb, nullptr, nullptr, SLEN, QKV3, HDIM);
  else
    gemm_nt<0, false><<<dim3(SLEN / 128, QKV3 / 128), 256, 0, stream>>>(
        ln, w_qkv, qkvb, nullptr, nullptr, SLEN, QKV3, HDIM);
  attn_fwd<<<dim3(NHEADS, SLEN / 64), 256, 0, stream>>>(qkvb, ctx);
  if (cvt)
    gemm_nt<1, true><<<dim3(SLEN / 128, HDIM / 128), 256, 0, stream>>>(
        ctx, watt16, nullptr, x1, hidden, SLEN, HDIM, HDIM);
  else
    gemm_nt<1, false><<<dim3(SLEN / 128, HDIM / 128), 256, 0, stream>>>(
        ctx, w_attn, nullptr, x1, hidden, SLEN, HDIM, HDIM);
  rmsnorm_k<<<SLEN, 256, 0, stream>>>(x1, w_norm2, ln);
  if (cvt)
    gemm_h4h<true><<<dim3(SLEN / 128, FFDIM / 64), 256, 0, stream>>>(
        ln, wh4h16, act, SLEN, HDIM);
  else
    gemm_h4h<false><<<dim3(SLEN / 128, FFDIM / 64), 256, 0, stream>>>(
        ln, w_h4h, act, SLEN, HDIM);
  gemm_down<<<dim3(SLEN / 128, HDIM / 128), 256, 0, stream>>>(
      act, qweight, qzeros, scales, x1, bias4h, out, SLEN, HDIM, FFDIM);
}